// Round 27
// baseline (86.925 us; speedup 1.0000x reference)
//
#include <hip/hip_runtime.h>

#define NC 32     // num_capsule
#define DC 16     // dim_capsule
#define INC 144   // input capsules
#define IND 8     // input dim
#define NT 512
#define LG_S 152  // halves per b row of logits

// ---- fused-kernel LDS layout (fallback path, r25 verbatim) ----
#define HATL_OFF 0
#define HATH_OFF (NC * INC * IND + 8)          // 36872; 16B-aligned
#define LG_OFF (HATH_OFF + NC * INC * IND)     // 73736; 16B-aligned
#define OB_OFF (LG_OFF + NC * LG_S)            // 78600; 16B-aligned
#define SMEM_HALVES (OB_OFF + NC * DC)         // 79112
#define SMEM_BYTES (SMEM_HALVES * 2)           // 158224 <= 163840

// ---- split-path sizes ----
#define WH_BYTES ((size_t)NC * INC * DC * IND * 2)        // 1179648
#define PLANE_HALVES ((size_t)512 * NC * INC * IND)       // 18,874,368 halves
#define PLANE_BYTES (PLANE_HALVES * 2)                    // 37,748,736
#define NEED_BYTES (WH_BYTES + 2 * PLANE_BYTES)           // 76,677,120
#define HSM_BYTES 73728                                   // hat_kernel LDS

typedef _Float16 h2 __attribute__((ext_vector_type(2)));
typedef _Float16 h4v __attribute__((ext_vector_type(4)));
typedef _Float16 h8 __attribute__((ext_vector_type(8)));
typedef float f4 __attribute__((ext_vector_type(4)));

union H8 { h8 v; h2 p[4]; _Float16 e[8]; };
union WU { uint4 u; h8 v; h2 p[4]; };

#if __has_builtin(__builtin_amdgcn_fdot2)
__device__ __forceinline__ float fdot2(h2 a, h2 b, float c) {
    return __builtin_amdgcn_fdot2(a, b, c, false);
}
#else
__device__ __forceinline__ float fdot2(h2 a, h2 b, float c) {
    return c + (float)a[0] * (float)b[0] + (float)a[1] * (float)b[1];
}
#endif

// Convert+TRANSPOSE W: fp32 [b][c][d][i] -> fp16 h8-slots; slot i = bk*256+d*16+cg,
// c = cg + 16k. 73728 h8 slots -> grid 288 x 256.
__global__ void convw_kernel(const float* __restrict__ W, _Float16* __restrict__ Wh) {
    int i = blockIdx.x * 256 + threadIdx.x;
    int cg = i & 15, d = (i >> 4) & 15, bk = i >> 8;
    int k = bk % 9, b = bk / 9;
    const float* s = W + (((size_t)b * INC + cg + 16 * k) * DC + d) * IND;
    f4 v0 = *reinterpret_cast<const f4*>(s);
    f4 v1 = *reinterpret_cast<const f4*>(s + 4);
    H8 o;
    o.e[0] = (_Float16)v0[0]; o.e[1] = (_Float16)v0[1];
    o.e[2] = (_Float16)v0[2]; o.e[3] = (_Float16)v0[3];
    o.e[4] = (_Float16)v1[0]; o.e[5] = (_Float16)v1[1];
    o.e[6] = (_Float16)v1[2]; o.e[7] = (_Float16)v1[3];
    *reinterpret_cast<h8*>(Wh + (size_t)i * 8) = o.v;
}

#define R8(M)  M(0) M(1) M(2) M(3) M(4) M(5) M(6) M(7)
#define R9(M)  M(0) M(1) M(2) M(3) M(4) M(5) M(6) M(7) M(8)
#define R16(M) M(0) M(1) M(2) M(3) M(4) M(5) M(6) M(7) M(8) M(9) M(10) M(11) M(12) M(13) M(14) M(15)

// =====================  SPLIT PATH: hat kernel  =====================
// grid 1024 = (achunk 0..31) x (b 0..31), NT 256: W[b] staged ONCE per 16
// batch elements -> W L2 traffic /16. hat rows -> global planes (row = cg*9+k).
__global__ __launch_bounds__(256)
void hat_kernel(const float* __restrict__ xg, const _Float16* __restrict__ Wh,
                _Float16* __restrict__ hatLg, _Float16* __restrict__ hatHg) {
    extern __shared__ __align__(16) _Float16 hsm[];
    _Float16* Wl = hsm;            // 2304 h8 rows = 36864 B
    _Float16* xl = hsm + 18432;    // 16 a x 144 c x 8 i fp16 = 36864 B

    const int t = threadIdx.x;
    const int b = blockIdx.x & 31;
    const int ach = blockIdx.x >> 5;

    // stage W[b]: 2304 h8, coalesced
    {
        const h8* src = reinterpret_cast<const h8*>(Wh + (size_t)b * 18432);
        h8* dst = reinterpret_cast<h8*>(Wl);
        #pragma unroll
        for (int j = 0; j < 9; ++j) dst[t + 256 * j] = src[t + 256 * j];
    }
    // stage x for 16 a's: 4608 f4 -> fp16
    {
        const f4* src = reinterpret_cast<const f4*>(xg) + (size_t)ach * 4608;
        #pragma unroll
        for (int j = 0; j < 18; ++j) {
            int i = t + 256 * j;
            f4 v = src[i];
            h4v hv;
            hv[0] = (_Float16)v[0]; hv[1] = (_Float16)v[1];
            hv[2] = (_Float16)v[2]; hv[3] = (_Float16)v[3];
            *reinterpret_cast<h4v*>(xl + (size_t)i * 4) = hv;
        }
    }
    __syncthreads();

    const int al = t >> 4, cg = t & 15;
    const size_t rowbase = (((size_t)(ach * 16 + al) * NC + b) * INC + cg * 9) * 8;

#define WD1(T, E, D) { \
    WU w; w.u = *reinterpret_cast<const uint4*>(Wl + ((kk * 16 + (D)) * 16 + cg) * 8); \
    float ac = fdot2(w.p[0], xv.p[0], 0.f); \
    ac = fdot2(w.p[1], xv.p[1], ac); \
    ac = fdot2(w.p[2], xv.p[2], ac); \
    ac = fdot2(w.p[3], xv.p[3], ac); \
    T.e[E] = (_Float16)ac; }

#define HK(K) { \
    const int kk = (K); \
    const int c = cg + 16 * kk; \
    H8 xv; xv.v = *reinterpret_cast<const h8*>(xl + ((size_t)al * INC + c) * 8); \
    H8 tL, tH; \
    WD1(tL,0,0) WD1(tL,1,1) WD1(tL,2,2) WD1(tL,3,3) \
    WD1(tL,4,4) WD1(tL,5,5) WD1(tL,6,6) WD1(tL,7,7) \
    WD1(tH,0,8) WD1(tH,1,9) WD1(tH,2,10) WD1(tH,3,11) \
    WD1(tH,4,12) WD1(tH,5,13) WD1(tH,6,14) WD1(tH,7,15) \
    *reinterpret_cast<h8*>(hatLg + rowbase + (size_t)kk * 8) = tL.v; \
    *reinterpret_cast<h8*>(hatHg + rowbase + (size_t)kk * 8) = tH.v; }

    R9(HK)
}

// =====================  SPLIT PATH: routing kernel  =====================
__global__ __launch_bounds__(NT)
__attribute__((amdgpu_waves_per_eu(2, 4)))
void route_kernel(const _Float16* __restrict__ hatLg, const _Float16* __restrict__ hatHg,
                  float* __restrict__ out) {
    extern __shared__ __align__(16) _Float16 sm[];
    _Float16* lg = sm + LG_OFF;
    _Float16* o_buf = sm + OB_OFF;

    const int t = threadIdx.x;
    const int b = t >> 4;
    const int cg = t & 15;
    const int a = blockIdx.x;

    // stage hat[a]: 4608 rows per plane, coalesced 16B/lane
    {
        const h8* srcL = reinterpret_cast<const h8*>(hatLg + (size_t)a * 36864);
        const h8* srcH = reinterpret_cast<const h8*>(hatHg + (size_t)a * 36864);
        #pragma unroll
        for (int j = 0; j < 9; ++j) {
            int i = t + NT * j;
            *reinterpret_cast<h8*>(sm + HATL_OFF + (size_t)i * 8) = srcL[i];
            *reinterpret_cast<h8*>(sm + HATH_OFF + (size_t)i * 8) = srcH[i];
        }
    }
    __syncthreads();

#define DECLS(D) float s##D;
    R16(DECLS)
#define ZEROS(D) s##D = 0.f;
    R16(ZEROS)

    // s0 pass: s_d = sum over own 9 rows (rows cg*9..cg*9+8 of own b)
#define S0STEP(K) { \
    const size_t r_ = ((size_t)b * INC + cg * 9 + (K)) * 8; \
    H8 hl, hh; \
    hl.v = *reinterpret_cast<const h8*>(sm + HATL_OFF + r_); \
    hh.v = *reinterpret_cast<const h8*>(sm + HATH_OFF + r_); \
    s0  += (float)hl.e[0];  s1  += (float)hl.e[1]; \
    s2  += (float)hl.e[2];  s3  += (float)hl.e[3]; \
    s4  += (float)hl.e[4];  s5  += (float)hl.e[5]; \
    s6  += (float)hl.e[6];  s7  += (float)hl.e[7]; \
    s8  += (float)hh.e[0];  s9  += (float)hh.e[1]; \
    s10 += (float)hh.e[2];  s11 += (float)hh.e[3]; \
    s12 += (float)hh.e[4];  s13 += (float)hh.e[5]; \
    s14 += (float)hh.e[6];  s15 += (float)hh.e[7]; }

    R9(S0STEP)

    const bool c8 = (cg & 8) != 0, c4 = (cg & 4) != 0;
    const bool c2 = (cg & 2) != 0, c1 = (cg & 1) != 0;
#define HV(A, B, M, CB) { float snd_ = (CB) ? s##A : s##B; \
                          float kp_ = (CB) ? s##B : s##A; \
                          s##A = kp_ + __shfl_xor(snd_, M, 16); }
#define HALVE16 \
    HV(0,8,8,c8) HV(1,9,8,c8) HV(2,10,8,c8) HV(3,11,8,c8) \
    HV(4,12,8,c8) HV(5,13,8,c8) HV(6,14,8,c8) HV(7,15,8,c8) \
    HV(0,4,4,c4) HV(1,5,4,c4) HV(2,6,4,c4) HV(3,7,4,c4) \
    HV(0,2,2,c2) HV(1,3,2,c2) \
    HV(0,1,1,c1)

#define SQUASH1(RS, OVAL) \
    float r_ = s0 * (RS); \
    float n2_ = r_ * r_; \
    n2_ += __shfl_xor(n2_, 1, 16); n2_ += __shfl_xor(n2_, 2, 16); \
    n2_ += __shfl_xor(n2_, 4, 16); n2_ += __shfl_xor(n2_, 8, 16); \
    float OVAL = r_ * (n2_ / ((1.0f + n2_) * sqrtf(n2_ + 1e-7f)));

#define OBCAST(OVAL) \
    o_buf[b * DC + cg] = (_Float16)(OVAL); \
    __threadfence_block(); \
    oLv = *reinterpret_cast<const h8*>(o_buf + b * DC); \
    oHv = *reinterpret_cast<const h8*>(o_buf + b * DC + 8);

    h8 oLv, oHv;
    HALVE16
    {
        SQUASH1(1.0f / 32.0f, oval)
        OBCAST(oval)
    }

#define DECLG(K) float lgr##K = 0.f;
    R9(DECLG)

#define RBSTEP(K) { \
    const size_t r_ = ((size_t)b * INC + cg * 9 + (K)) * 8; \
    const int c = cg + 16 * (K); \
    H8 hl, hh; \
    hl.v = *reinterpret_cast<const h8*>(sm + HATL_OFF + r_); \
    hh.v = *reinterpret_cast<const h8*>(sm + HATH_OFF + r_); \
    H8 ol, oh; ol.v = oLv; oh.v = oHv; \
    float dt  = fdot2(hl.p[0], ol.p[0], 0.f); \
    float dt2 = fdot2(hl.p[1], ol.p[1], 0.f); \
    dt  = fdot2(hl.p[2], ol.p[2], dt); \
    dt2 = fdot2(hl.p[3], ol.p[3], dt2); \
    dt  = fdot2(hh.p[0], oh.p[0], dt); \
    dt2 = fdot2(hh.p[1], oh.p[1], dt2); \
    dt  = fdot2(hh.p[2], oh.p[2], dt); \
    dt2 = fdot2(hh.p[3], oh.p[3], dt2); \
    lgr##K += dt + dt2; \
    lg[b * LG_S + c] = (_Float16)lgr##K; }

#define RSSTEP(K) { \
    const size_t r_ = ((size_t)b * INC + cg * 9 + (K)) * 8; \
    const int c = cg + 16 * (K); \
    float cf = (float)lg[b * LG_S + c]; \
    H8 hl, hh; \
    hl.v = *reinterpret_cast<const h8*>(sm + HATL_OFF + r_); \
    hh.v = *reinterpret_cast<const h8*>(sm + HATH_OFF + r_); \
    s0  = fmaf(cf, (float)hl.e[0], s0);  s1  = fmaf(cf, (float)hl.e[1], s1); \
    s2  = fmaf(cf, (float)hl.e[2], s2);  s3  = fmaf(cf, (float)hl.e[3], s3); \
    s4  = fmaf(cf, (float)hl.e[4], s4);  s5  = fmaf(cf, (float)hl.e[5], s5); \
    s6  = fmaf(cf, (float)hl.e[6], s6);  s7  = fmaf(cf, (float)hl.e[7], s7); \
    s8  = fmaf(cf, (float)hh.e[0], s8);  s9  = fmaf(cf, (float)hh.e[1], s9); \
    s10 = fmaf(cf, (float)hh.e[2], s10); s11 = fmaf(cf, (float)hh.e[3], s11); \
    s12 = fmaf(cf, (float)hh.e[4], s12); s13 = fmaf(cf, (float)hh.e[5], s13); \
    s14 = fmaf(cf, (float)hh.e[6], s14); s15 = fmaf(cf, (float)hh.e[7], s15); }

    for (int it = 0; it < 2; ++it) {
        R9(RBSTEP)
        __syncthreads();

        if (t < 2 * INC) {
            const int c = t >> 1;
            const int rb = (t & 1) * 16;
#define SMR(I) float v##I = (float)lg[(rb + I) * LG_S + c];
            R16(SMR)
            float m = fmaxf(v0, v1);
#define SMM(I) m = fmaxf(m, v##I);
            SMM(2) SMM(3) SMM(4) SMM(5) SMM(6) SMM(7) SMM(8) SMM(9)
            SMM(10) SMM(11) SMM(12) SMM(13) SMM(14) SMM(15)
            m = fmaxf(m, __shfl_xor(m, 1));
            float S = 0.f;
#define SME(I) v##I = __expf(v##I - m); S += v##I;
            R16(SME)
            S += __shfl_xor(S, 1);
            float inv = 1.0f / S;
#define SMW(I) lg[(rb + I) * LG_S + c] = (_Float16)(v##I * inv);
            R16(SMW)
        }
        __syncthreads();

        R16(ZEROS)
        R9(RSSTEP)
        HALVE16

        if (it == 0) {
            SQUASH1(1.0f, oval)
            OBCAST(oval)
            __syncthreads();
        } else {
            SQUASH1(1.0f, oval)
            out[(size_t)a * (NC * DC) + t] = oval;
        }
    }
}

// =====================  FUSED FALLBACK (r25 verbatim)  =====================
template <typename WT>
__global__ __launch_bounds__(NT)
__attribute__((amdgpu_waves_per_eu(2, 4)))
void caps_kernel(const float* __restrict__ xg, const WT* __restrict__ Wg,
                 float* __restrict__ out) {
    extern __shared__ __align__(16) _Float16 sm[];
    _Float16* lg = sm + LG_OFF;
    _Float16* o_buf = sm + OB_OFF;
    _Float16* x_h = lg;

    const int t = threadIdx.x;
    const int b = t >> 4;
    const int cg = t & 15;
    const int a = blockIdx.x;

    if (t < 288) {
        f4 v = reinterpret_cast<const f4*>(xg + (size_t)a * (INC * IND))[t];
        h4v hv;
        hv[0] = (_Float16)v[0]; hv[1] = (_Float16)v[1];
        hv[2] = (_Float16)v[2]; hv[3] = (_Float16)v[3];
        *reinterpret_cast<h4v*>(x_h + t * 4) = hv;
    }
    __syncthreads();

    R16(DECLS)
    R16(ZEROS)

#define WADDR(K, DG) reinterpret_cast<const uint4*>( \
    reinterpret_cast<const char*>(Wg) + (size_t)(b * 9 + (K)) * 4096 + (DG) * 256 + cg * 16)

#define PREA(K) { wA0 = *WADDR(K,0); wA1 = *WADDR(K,1); wA2 = *WADDR(K,2); \
                  wA3 = *WADDR(K,3); wA4 = *WADDR(K,4); wA5 = *WADDR(K,5); \
                  wA6 = *WADDR(K,6); wA7 = *WADDR(K,7); }
#define PREB(K) { wB0 = *WADDR(K,8); wB1 = *WADDR(K,9); wB2 = *WADDR(K,10); \
                  wB3 = *WADDR(K,11); wB4 = *WADDR(K,12); wB5 = *WADDR(K,13); \
                  wB6 = *WADDR(K,14); wB7 = *WADDR(K,15); }

#define HD1R(WREG, T, E, SD) { \
    WU w; w.u = WREG; \
    float ac = fdot2(w.p[0], xv.p[0], 0.f); \
    ac = fdot2(w.p[1], xv.p[1], ac); \
    ac = fdot2(w.p[2], xv.p[2], ac); \
    ac = fdot2(w.p[3], xv.p[3], ac); \
    T.e[E] = (_Float16)ac; s##SD += ac; }

#define CMPA(T) HD1R(wA0,T,0,0) HD1R(wA1,T,1,1) HD1R(wA2,T,2,2) HD1R(wA3,T,3,3) \
                HD1R(wA4,T,4,4) HD1R(wA5,T,5,5) HD1R(wA6,T,6,6) HD1R(wA7,T,7,7)
#define CMPB(T) HD1R(wB0,T,0,8) HD1R(wB1,T,1,9) HD1R(wB2,T,2,10) HD1R(wB3,T,3,11) \
                HD1R(wB4,T,4,12) HD1R(wB5,T,5,13) HD1R(wB6,T,6,14) HD1R(wB7,T,7,15)

#define HPIPE(K, KN) { \
    const int c = cg + 16 * (K); \
    H8 xv; xv.v = *reinterpret_cast<const h8*>(x_h + c * IND); \
    H8 tL, tH; \
    CMPA(tL) \
    PREA(KN) \
    CMPB(tH) \
    PREB(KN) \
    *reinterpret_cast<h8*>(sm + HATL_OFF + (size_t)(b * INC + c) * 8) = tL.v; \
    *reinterpret_cast<h8*>(sm + HATH_OFF + (size_t)(b * INC + c) * 8) = tH.v; }

#define HD1F(T, E, DG) { \
    const float* wf = wfr + (DG) * IND; \
    f4 w0 = *reinterpret_cast<const f4*>(wf); \
    f4 w1 = *reinterpret_cast<const f4*>(wf + 4); \
    float ac = (float)xv.e[0] * w0[0]; \
    ac = fmaf((float)xv.e[1], w0[1], ac); \
    ac = fmaf((float)xv.e[2], w0[2], ac); \
    ac = fmaf((float)xv.e[3], w0[3], ac); \
    ac = fmaf((float)xv.e[4], w1[0], ac); \
    ac = fmaf((float)xv.e[5], w1[1], ac); \
    ac = fmaf((float)xv.e[6], w1[2], ac); \
    ac = fmaf((float)xv.e[7], w1[3], ac); \
    T.e[E] = (_Float16)ac; s##DG += ac; }

#define HSTEPF(K) { \
    const int c = cg + 16 * (K); \
    H8 xv; xv.v = *reinterpret_cast<const h8*>(x_h + c * IND); \
    const float* wfr = reinterpret_cast<const float*>(Wg) + \
                       (size_t)(b * INC + c) * (DC * IND); \
    H8 tL, tH; \
    HD1F(tL,0,0) HD1F(tL,1,1) HD1F(tL,2,2) HD1F(tL,3,3) \
    HD1F(tL,4,4) HD1F(tL,5,5) HD1F(tL,6,6) HD1F(tL,7,7) \
    HD1F(tH,0,8) HD1F(tH,1,9) HD1F(tH,2,10) HD1F(tH,3,11) \
    HD1F(tH,4,12) HD1F(tH,5,13) HD1F(tH,6,14) HD1F(tH,7,15) \
    *reinterpret_cast<h8*>(sm + HATL_OFF + (size_t)(b * INC + c) * 8) = tL.v; \
    *reinterpret_cast<h8*>(sm + HATH_OFF + (size_t)(b * INC + c) * 8) = tH.v; }

    if constexpr (sizeof(WT) == 2) {
        uint4 wA0, wA1, wA2, wA3, wA4, wA5, wA6, wA7;
        uint4 wB0, wB1, wB2, wB3, wB4, wB5, wB6, wB7;
        PREA(0) PREB(0)
        HPIPE(0, 1) HPIPE(1, 2) HPIPE(2, 3) HPIPE(3, 4) HPIPE(4, 5)
        HPIPE(5, 6) HPIPE(6, 7) HPIPE(7, 8) HPIPE(8, 8)
    } else {
        R9(HSTEPF)
    }
    __syncthreads();

    const bool c8 = (cg & 8) != 0, c4 = (cg & 4) != 0;
    const bool c2 = (cg & 2) != 0, c1 = (cg & 1) != 0;

    h8 oLv, oHv;
    HALVE16
    {
        SQUASH1(1.0f / 32.0f, oval)
        OBCAST(oval)
    }

    R9(DECLG)

#define BSTEP(K) { \
    const int c = cg + 16 * (K); \
    H8 hl, hh; \
    hl.v = *reinterpret_cast<const h8*>(sm + HATL_OFF + (size_t)(b * INC + c) * 8); \
    hh.v = *reinterpret_cast<const h8*>(sm + HATH_OFF + (size_t)(b * INC + c) * 8); \
    H8 ol, oh; ol.v = oLv; oh.v = oHv; \
    float dt  = fdot2(hl.p[0], ol.p[0], 0.f); \
    float dt2 = fdot2(hl.p[1], ol.p[1], 0.f); \
    dt  = fdot2(hl.p[2], ol.p[2], dt); \
    dt2 = fdot2(hl.p[3], ol.p[3], dt2); \
    dt  = fdot2(hh.p[0], oh.p[0], dt); \
    dt2 = fdot2(hh.p[1], oh.p[1], dt2); \
    dt  = fdot2(hh.p[2], oh.p[2], dt); \
    dt2 = fdot2(hh.p[3], oh.p[3], dt2); \
    lgr##K += dt + dt2; \
    lg[b * LG_S + c] = (_Float16)lgr##K; }

#define SSTEP(K) { \
    const int c = cg + 16 * (K); \
    float cf = (float)lg[b * LG_S + c]; \
    H8 hl, hh; \
    hl.v = *reinterpret_cast<const h8*>(sm + HATL_OFF + (size_t)(b * INC + c) * 8); \
    hh.v = *reinterpret_cast<const h8*>(sm + HATH_OFF + (size_t)(b * INC + c) * 8); \
    s0  = fmaf(cf, (float)hl.e[0], s0);  s1  = fmaf(cf, (float)hl.e[1], s1); \
    s2  = fmaf(cf, (float)hl.e[2], s2);  s3  = fmaf(cf, (float)hl.e[3], s3); \
    s4  = fmaf(cf, (float)hl.e[4], s4);  s5  = fmaf(cf, (float)hl.e[5], s5); \
    s6  = fmaf(cf, (float)hl.e[6], s6);  s7  = fmaf(cf, (float)hl.e[7], s7); \
    s8  = fmaf(cf, (float)hh.e[0], s8);  s9  = fmaf(cf, (float)hh.e[1], s9); \
    s10 = fmaf(cf, (float)hh.e[2], s10); s11 = fmaf(cf, (float)hh.e[3], s11); \
    s12 = fmaf(cf, (float)hh.e[4], s12); s13 = fmaf(cf, (float)hh.e[5], s13); \
    s14 = fmaf(cf, (float)hh.e[6], s14); s15 = fmaf(cf, (float)hh.e[7], s15); }

    for (int it = 0; it < 2; ++it) {
        R9(BSTEP)
        __syncthreads();

        if (t < 2 * INC) {
            const int c = t >> 1;
            const int rb = (t & 1) * 16;
            R16(SMR)
            float m = fmaxf(v0, v1);
            SMM(2) SMM(3) SMM(4) SMM(5) SMM(6) SMM(7) SMM(8) SMM(9)
            SMM(10) SMM(11) SMM(12) SMM(13) SMM(14) SMM(15)
            m = fmaxf(m, __shfl_xor(m, 1));
            float S = 0.f;
            R16(SME)
            S += __shfl_xor(S, 1);
            float inv = 1.0f / S;
            R16(SMW)
        }
        __syncthreads();

        R16(ZEROS)
        R9(SSTEP)
        HALVE16

        if (it == 0) {
            SQUASH1(1.0f, oval)
            OBCAST(oval)
            __syncthreads();
        } else {
            SQUASH1(1.0f, oval)
            out[(size_t)a * (NC * DC) + t] = oval;
        }
    }
}

extern "C" void kernel_launch(void* const* d_in, const int* in_sizes, int n_in,
                              void* d_out, int out_size, void* d_ws, size_t ws_size,
                              hipStream_t stream) {
    const float* x = (const float*)d_in[0];
    const float* W = (const float*)d_in[1];
    float* out = (float*)d_out;

    if (ws_size >= NEED_BYTES) {
        _Float16* Wh = (_Float16*)d_ws;
        _Float16* hatLg = (_Float16*)((char*)d_ws + WH_BYTES);
        _Float16* hatHg = (_Float16*)((char*)d_ws + WH_BYTES + PLANE_BYTES);
        hipLaunchKernelGGL(convw_kernel, dim3(288), dim3(256), 0, stream, W, Wh);
        hipFuncSetAttribute(reinterpret_cast<const void*>(&hat_kernel),
                            hipFuncAttributeMaxDynamicSharedMemorySize, HSM_BYTES);
        hipLaunchKernelGGL(hat_kernel, dim3(1024), dim3(256), HSM_BYTES, stream,
                           x, Wh, hatLg, hatHg);
        hipFuncSetAttribute(reinterpret_cast<const void*>(&route_kernel),
                            hipFuncAttributeMaxDynamicSharedMemorySize, SMEM_BYTES);
        hipLaunchKernelGGL(route_kernel, dim3(512), dim3(NT), SMEM_BYTES, stream,
                           hatLg, hatHg, out);
    } else if (ws_size >= WH_BYTES) {
        _Float16* Wh = (_Float16*)d_ws;
        hipLaunchKernelGGL(convw_kernel, dim3(288), dim3(256), 0, stream, W, Wh);
        hipFuncSetAttribute(reinterpret_cast<const void*>(&caps_kernel<_Float16>),
                            hipFuncAttributeMaxDynamicSharedMemorySize, SMEM_BYTES);
        hipLaunchKernelGGL(caps_kernel<_Float16>, dim3(512), dim3(NT), SMEM_BYTES,
                           stream, x, Wh, out);
    } else {
        hipFuncSetAttribute(reinterpret_cast<const void*>(&caps_kernel<float>),
                            hipFuncAttributeMaxDynamicSharedMemorySize, SMEM_BYTES);
        hipLaunchKernelGGL(caps_kernel<float>, dim3(512), dim3(NT), SMEM_BYTES,
                           stream, x, W, out);
    }
}

// Round 28
// 54.231 us; speedup vs baseline: 1.6029x; 1.6029x over previous
//
#include <hip/hip_runtime.h>

#define NC 32     // num_capsule
#define DC 16     // dim_capsule
#define INC 144   // input capsules
#define IND 8     // input dim
#define NT 512
#define LG_S 152  // halves per b row of logits

// ---- fused-kernel LDS layout (also used by route_kernel) ----
#define HATL_OFF 0
#define HATH_OFF (NC * INC * IND + 8)          // 36872; 16B-aligned
#define LG_OFF (HATH_OFF + NC * INC * IND)     // 73736; 16B-aligned
#define OB_OFF (LG_OFF + NC * LG_S)            // 78600; 16B-aligned
#define SMEM_HALVES (OB_OFF + NC * DC)         // 79112
#define SMEM_BYTES (SMEM_HALVES * 2)           // 158224 <= 163840

// ---- split-path sizes ----
#define WH_BYTES ((size_t)NC * INC * DC * IND * 2)        // 1179648
#define PLANE_HALVES ((size_t)512 * NC * INC * IND)       // 18,874,368 halves
#define PLANE_BYTES (PLANE_HALVES * 2)                    // 37,748,736
#define NEED_BYTES (WH_BYTES + 2 * PLANE_BYTES)           // 76,677,120
#define HSM_BYTES 73728                                   // hat_kernel LDS

typedef _Float16 h2 __attribute__((ext_vector_type(2)));
typedef _Float16 h4v __attribute__((ext_vector_type(4)));
typedef _Float16 h8 __attribute__((ext_vector_type(8)));
typedef float f4 __attribute__((ext_vector_type(4)));

union H8 { h8 v; h2 p[4]; _Float16 e[8]; };
union WU { uint4 u; h8 v; h2 p[4]; };

#if __has_builtin(__builtin_amdgcn_fdot2)
__device__ __forceinline__ float fdot2(h2 a, h2 b, float c) {
    return __builtin_amdgcn_fdot2(a, b, c, false);
}
#else
__device__ __forceinline__ float fdot2(h2 a, h2 b, float c) {
    return c + (float)a[0] * (float)b[0] + (float)a[1] * (float)b[1];
}
#endif

// Convert+TRANSPOSE W: fp32 [b][c][d][i] -> fp16 h8-slots; slot i = bk*256+d*16+cg,
// c = cg + 16k. 73728 h8 slots -> grid 288 x 256.
__global__ void convw_kernel(const float* __restrict__ W, _Float16* __restrict__ Wh) {
    int i = blockIdx.x * 256 + threadIdx.x;
    int cg = i & 15, d = (i >> 4) & 15, bk = i >> 8;
    int k = bk % 9, b = bk / 9;
    const float* s = W + (((size_t)b * INC + cg + 16 * k) * DC + d) * IND;
    f4 v0 = *reinterpret_cast<const f4*>(s);
    f4 v1 = *reinterpret_cast<const f4*>(s + 4);
    H8 o;
    o.e[0] = (_Float16)v0[0]; o.e[1] = (_Float16)v0[1];
    o.e[2] = (_Float16)v0[2]; o.e[3] = (_Float16)v0[3];
    o.e[4] = (_Float16)v1[0]; o.e[5] = (_Float16)v1[1];
    o.e[6] = (_Float16)v1[2]; o.e[7] = (_Float16)v1[3];
    *reinterpret_cast<h8*>(Wh + (size_t)i * 8) = o.v;
}

#define R8(M)  M(0) M(1) M(2) M(3) M(4) M(5) M(6) M(7)
#define R9(M)  M(0) M(1) M(2) M(3) M(4) M(5) M(6) M(7) M(8)
#define R16(M) M(0) M(1) M(2) M(3) M(4) M(5) M(6) M(7) M(8) M(9) M(10) M(11) M(12) M(13) M(14) M(15)

// =====================  SPLIT PATH: hat kernel  =====================
// grid 1024 = (achunk 0..31) x (b 0..31), NT 256: W[b] staged ONCE per 16
// batch elements. Hat planes in NATURAL c order: row = (a*NC+b)*INC + c,
// c = cg+16k -> at fixed k the 16 cg-lanes write one contiguous 256B segment
// (r27 bug: cg*9+k order gave 144B-stride 16B stores -> 3x write amplification).
__global__ __launch_bounds__(256)
void hat_kernel(const float* __restrict__ xg, const _Float16* __restrict__ Wh,
                _Float16* __restrict__ hatLg, _Float16* __restrict__ hatHg) {
    extern __shared__ __align__(16) _Float16 hsm[];
    _Float16* Wl = hsm;            // 2304 h8 rows = 36864 B
    _Float16* xl = hsm + 18432;    // 16 a x 144 c x 8 i fp16 = 36864 B

    const int t = threadIdx.x;
    const int b = blockIdx.x & 31;
    const int ach = blockIdx.x >> 5;

    // stage W[b]: 2304 h8, coalesced
    {
        const h8* src = reinterpret_cast<const h8*>(Wh + (size_t)b * 18432);
        h8* dst = reinterpret_cast<h8*>(Wl);
        #pragma unroll
        for (int j = 0; j < 9; ++j) dst[t + 256 * j] = src[t + 256 * j];
    }
    // stage x for 16 a's: 4608 f4 -> fp16
    {
        const f4* src = reinterpret_cast<const f4*>(xg) + (size_t)ach * 4608;
        #pragma unroll
        for (int j = 0; j < 18; ++j) {
            int i = t + 256 * j;
            f4 v = src[i];
            h4v hv;
            hv[0] = (_Float16)v[0]; hv[1] = (_Float16)v[1];
            hv[2] = (_Float16)v[2]; hv[3] = (_Float16)v[3];
            *reinterpret_cast<h4v*>(xl + (size_t)i * 4) = hv;
        }
    }
    __syncthreads();

    const int al = t >> 4, cg = t & 15;
    const size_t rowbase = (((size_t)(ach * 16 + al) * NC + b) * INC) * 8;

#define WD1(T, E, D) { \
    WU w; w.u = *reinterpret_cast<const uint4*>(Wl + ((kk * 16 + (D)) * 16 + cg) * 8); \
    float ac = fdot2(w.p[0], xv.p[0], 0.f); \
    ac = fdot2(w.p[1], xv.p[1], ac); \
    ac = fdot2(w.p[2], xv.p[2], ac); \
    ac = fdot2(w.p[3], xv.p[3], ac); \
    T.e[E] = (_Float16)ac; }

#define HK(K) { \
    const int kk = (K); \
    const int c = cg + 16 * kk; \
    H8 xv; xv.v = *reinterpret_cast<const h8*>(xl + ((size_t)al * INC + c) * 8); \
    H8 tL, tH; \
    WD1(tL,0,0) WD1(tL,1,1) WD1(tL,2,2) WD1(tL,3,3) \
    WD1(tL,4,4) WD1(tL,5,5) WD1(tL,6,6) WD1(tL,7,7) \
    WD1(tH,0,8) WD1(tH,1,9) WD1(tH,2,10) WD1(tH,3,11) \
    WD1(tH,4,12) WD1(tH,5,13) WD1(tH,6,14) WD1(tH,7,15) \
    *reinterpret_cast<h8*>(hatLg + rowbase + (size_t)c * 8) = tL.v; \
    *reinterpret_cast<h8*>(hatHg + rowbase + (size_t)c * 8) = tH.v; }

    R9(HK)
}

// =====================  SPLIT PATH: routing kernel  =====================
__global__ __launch_bounds__(NT)
__attribute__((amdgpu_waves_per_eu(2, 4)))
void route_kernel(const _Float16* __restrict__ hatLg, const _Float16* __restrict__ hatHg,
                  float* __restrict__ out) {
    extern __shared__ __align__(16) _Float16 sm[];
    _Float16* lg = sm + LG_OFF;
    _Float16* o_buf = sm + OB_OFF;

    const int t = threadIdx.x;
    const int b = t >> 4;
    const int cg = t & 15;
    const int a = blockIdx.x;

    // stage hat[a]: 4608 h8 rows per plane, coalesced 16B/lane
    {
        const h8* srcL = reinterpret_cast<const h8*>(hatLg + (size_t)a * 36864);
        const h8* srcH = reinterpret_cast<const h8*>(hatHg + (size_t)a * 36864);
        #pragma unroll
        for (int j = 0; j < 9; ++j) {
            int i = t + NT * j;
            *reinterpret_cast<h8*>(sm + HATL_OFF + (size_t)i * 8) = srcL[i];
            *reinterpret_cast<h8*>(sm + HATH_OFF + (size_t)i * 8) = srcH[i];
        }
    }
    __syncthreads();

#define DECLS(D) float s##D;
    R16(DECLS)
#define ZEROS(D) s##D = 0.f;
    R16(ZEROS)

    // s0 pass: add-only over own 9 c's (natural c = cg+16K rows, r25 pattern)
#define S0STEP(K) { \
    const size_t r_ = ((size_t)b * INC + cg + 16 * (K)) * 8; \
    H8 hl, hh; \
    hl.v = *reinterpret_cast<const h8*>(sm + HATL_OFF + r_); \
    hh.v = *reinterpret_cast<const h8*>(sm + HATH_OFF + r_); \
    s0  += (float)hl.e[0];  s1  += (float)hl.e[1]; \
    s2  += (float)hl.e[2];  s3  += (float)hl.e[3]; \
    s4  += (float)hl.e[4];  s5  += (float)hl.e[5]; \
    s6  += (float)hl.e[6];  s7  += (float)hl.e[7]; \
    s8  += (float)hh.e[0];  s9  += (float)hh.e[1]; \
    s10 += (float)hh.e[2];  s11 += (float)hh.e[3]; \
    s12 += (float)hh.e[4];  s13 += (float)hh.e[5]; \
    s14 += (float)hh.e[6];  s15 += (float)hh.e[7]; }

    R9(S0STEP)

    const bool c8 = (cg & 8) != 0, c4 = (cg & 4) != 0;
    const bool c2 = (cg & 2) != 0, c1 = (cg & 1) != 0;
#define HV(A, B, M, CB) { float snd_ = (CB) ? s##A : s##B; \
                          float kp_ = (CB) ? s##B : s##A; \
                          s##A = kp_ + __shfl_xor(snd_, M, 16); }
#define HALVE16 \
    HV(0,8,8,c8) HV(1,9,8,c8) HV(2,10,8,c8) HV(3,11,8,c8) \
    HV(4,12,8,c8) HV(5,13,8,c8) HV(6,14,8,c8) HV(7,15,8,c8) \
    HV(0,4,4,c4) HV(1,5,4,c4) HV(2,6,4,c4) HV(3,7,4,c4) \
    HV(0,2,2,c2) HV(1,3,2,c2) \
    HV(0,1,1,c1)

#define SQUASH1(RS, OVAL) \
    float r_ = s0 * (RS); \
    float n2_ = r_ * r_; \
    n2_ += __shfl_xor(n2_, 1, 16); n2_ += __shfl_xor(n2_, 2, 16); \
    n2_ += __shfl_xor(n2_, 4, 16); n2_ += __shfl_xor(n2_, 8, 16); \
    float OVAL = r_ * (n2_ / ((1.0f + n2_) * sqrtf(n2_ + 1e-7f)));

#define OBCAST(OVAL) \
    o_buf[b * DC + cg] = (_Float16)(OVAL); \
    __threadfence_block(); \
    oLv = *reinterpret_cast<const h8*>(o_buf + b * DC); \
    oHv = *reinterpret_cast<const h8*>(o_buf + b * DC + 8);

    h8 oLv, oHv;
    HALVE16
    {
        SQUASH1(1.0f / 32.0f, oval)
        OBCAST(oval)
    }

#define DECLG(K) float lgr##K = 0.f;
    R9(DECLG)

#define RBSTEP(K) { \
    const int c = cg + 16 * (K); \
    const size_t r_ = ((size_t)b * INC + c) * 8; \
    H8 hl, hh; \
    hl.v = *reinterpret_cast<const h8*>(sm + HATL_OFF + r_); \
    hh.v = *reinterpret_cast<const h8*>(sm + HATH_OFF + r_); \
    H8 ol, oh; ol.v = oLv; oh.v = oHv; \
    float dt  = fdot2(hl.p[0], ol.p[0], 0.f); \
    float dt2 = fdot2(hl.p[1], ol.p[1], 0.f); \
    dt  = fdot2(hl.p[2], ol.p[2], dt); \
    dt2 = fdot2(hl.p[3], ol.p[3], dt2); \
    dt  = fdot2(hh.p[0], oh.p[0], dt); \
    dt2 = fdot2(hh.p[1], oh.p[1], dt2); \
    dt  = fdot2(hh.p[2], oh.p[2], dt); \
    dt2 = fdot2(hh.p[3], oh.p[3], dt2); \
    lgr##K += dt + dt2; \
    lg[b * LG_S + c] = (_Float16)lgr##K; }

#define RSSTEP(K) { \
    const int c = cg + 16 * (K); \
    const size_t r_ = ((size_t)b * INC + c) * 8; \
    float cf = (float)lg[b * LG_S + c]; \
    H8 hl, hh; \
    hl.v = *reinterpret_cast<const h8*>(sm + HATL_OFF + r_); \
    hh.v = *reinterpret_cast<const h8*>(sm + HATH_OFF + r_); \
    s0  = fmaf(cf, (float)hl.e[0], s0);  s1  = fmaf(cf, (float)hl.e[1], s1); \
    s2  = fmaf(cf, (float)hl.e[2], s2);  s3  = fmaf(cf, (float)hl.e[3], s3); \
    s4  = fmaf(cf, (float)hl.e[4], s4);  s5  = fmaf(cf, (float)hl.e[5], s5); \
    s6  = fmaf(cf, (float)hl.e[6], s6);  s7  = fmaf(cf, (float)hl.e[7], s7); \
    s8  = fmaf(cf, (float)hh.e[0], s8);  s9  = fmaf(cf, (float)hh.e[1], s9); \
    s10 = fmaf(cf, (float)hh.e[2], s10); s11 = fmaf(cf, (float)hh.e[3], s11); \
    s12 = fmaf(cf, (float)hh.e[4], s12); s13 = fmaf(cf, (float)hh.e[5], s13); \
    s14 = fmaf(cf, (float)hh.e[6], s14); s15 = fmaf(cf, (float)hh.e[7], s15); }

    for (int it = 0; it < 2; ++it) {
        R9(RBSTEP)
        __syncthreads();

        if (t < 2 * INC) {
            const int c = t >> 1;
            const int rb = (t & 1) * 16;
#define SMR(I) float v##I = (float)lg[(rb + I) * LG_S + c];
            R16(SMR)
            float m = fmaxf(v0, v1);
#define SMM(I) m = fmaxf(m, v##I);
            SMM(2) SMM(3) SMM(4) SMM(5) SMM(6) SMM(7) SMM(8) SMM(9)
            SMM(10) SMM(11) SMM(12) SMM(13) SMM(14) SMM(15)
            m = fmaxf(m, __shfl_xor(m, 1));
            float S = 0.f;
#define SME(I) v##I = __expf(v##I - m); S += v##I;
            R16(SME)
            S += __shfl_xor(S, 1);
            float inv = 1.0f / S;
#define SMW(I) lg[(rb + I) * LG_S + c] = (_Float16)(v##I * inv);
            R16(SMW)
        }
        __syncthreads();

        R16(ZEROS)
        R9(RSSTEP)
        HALVE16

        if (it == 0) {
            SQUASH1(1.0f, oval)
            OBCAST(oval)
            __syncthreads();
        } else {
            SQUASH1(1.0f, oval)
            out[(size_t)a * (NC * DC) + t] = oval;
        }
    }
}

// =====================  FUSED FALLBACK (r25 verbatim)  =====================
template <typename WT>
__global__ __launch_bounds__(NT)
__attribute__((amdgpu_waves_per_eu(2, 4)))
void caps_kernel(const float* __restrict__ xg, const WT* __restrict__ Wg,
                 float* __restrict__ out) {
    extern __shared__ __align__(16) _Float16 sm[];
    _Float16* lg = sm + LG_OFF;
    _Float16* o_buf = sm + OB_OFF;
    _Float16* x_h = lg;

    const int t = threadIdx.x;
    const int b = t >> 4;
    const int cg = t & 15;
    const int a = blockIdx.x;

    if (t < 288) {
        f4 v = reinterpret_cast<const f4*>(xg + (size_t)a * (INC * IND))[t];
        h4v hv;
        hv[0] = (_Float16)v[0]; hv[1] = (_Float16)v[1];
        hv[2] = (_Float16)v[2]; hv[3] = (_Float16)v[3];
        *reinterpret_cast<h4v*>(x_h + t * 4) = hv;
    }
    __syncthreads();

    R16(DECLS)
    R16(ZEROS)

#define WADDR(K, DG) reinterpret_cast<const uint4*>( \
    reinterpret_cast<const char*>(Wg) + (size_t)(b * 9 + (K)) * 4096 + (DG) * 256 + cg * 16)

#define PREA(K) { wA0 = *WADDR(K,0); wA1 = *WADDR(K,1); wA2 = *WADDR(K,2); \
                  wA3 = *WADDR(K,3); wA4 = *WADDR(K,4); wA5 = *WADDR(K,5); \
                  wA6 = *WADDR(K,6); wA7 = *WADDR(K,7); }
#define PREB(K) { wB0 = *WADDR(K,8); wB1 = *WADDR(K,9); wB2 = *WADDR(K,10); \
                  wB3 = *WADDR(K,11); wB4 = *WADDR(K,12); wB5 = *WADDR(K,13); \
                  wB6 = *WADDR(K,14); wB7 = *WADDR(K,15); }

#define HD1R(WREG, T, E, SD) { \
    WU w; w.u = WREG; \
    float ac = fdot2(w.p[0], xv.p[0], 0.f); \
    ac = fdot2(w.p[1], xv.p[1], ac); \
    ac = fdot2(w.p[2], xv.p[2], ac); \
    ac = fdot2(w.p[3], xv.p[3], ac); \
    T.e[E] = (_Float16)ac; s##SD += ac; }

#define CMPA(T) HD1R(wA0,T,0,0) HD1R(wA1,T,1,1) HD1R(wA2,T,2,2) HD1R(wA3,T,3,3) \
                HD1R(wA4,T,4,4) HD1R(wA5,T,5,5) HD1R(wA6,T,6,6) HD1R(wA7,T,7,7)
#define CMPB(T) HD1R(wB0,T,0,8) HD1R(wB1,T,1,9) HD1R(wB2,T,2,10) HD1R(wB3,T,3,11) \
                HD1R(wB4,T,4,12) HD1R(wB5,T,5,13) HD1R(wB6,T,6,14) HD1R(wB7,T,7,15)

#define HPIPE(K, KN) { \
    const int c = cg + 16 * (K); \
    H8 xv; xv.v = *reinterpret_cast<const h8*>(x_h + c * IND); \
    H8 tL, tH; \
    CMPA(tL) \
    PREA(KN) \
    CMPB(tH) \
    PREB(KN) \
    *reinterpret_cast<h8*>(sm + HATL_OFF + (size_t)(b * INC + c) * 8) = tL.v; \
    *reinterpret_cast<h8*>(sm + HATH_OFF + (size_t)(b * INC + c) * 8) = tH.v; }

#define HD1F(T, E, DG) { \
    const float* wf = wfr + (DG) * IND; \
    f4 w0 = *reinterpret_cast<const f4*>(wf); \
    f4 w1 = *reinterpret_cast<const f4*>(wf + 4); \
    float ac = (float)xv.e[0] * w0[0]; \
    ac = fmaf((float)xv.e[1], w0[1], ac); \
    ac = fmaf((float)xv.e[2], w0[2], ac); \
    ac = fmaf((float)xv.e[3], w0[3], ac); \
    ac = fmaf((float)xv.e[4], w1[0], ac); \
    ac = fmaf((float)xv.e[5], w1[1], ac); \
    ac = fmaf((float)xv.e[6], w1[2], ac); \
    ac = fmaf((float)xv.e[7], w1[3], ac); \
    T.e[E] = (_Float16)ac; s##DG += ac; }

#define HSTEPF(K) { \
    const int c = cg + 16 * (K); \
    H8 xv; xv.v = *reinterpret_cast<const h8*>(x_h + c * IND); \
    const float* wfr = reinterpret_cast<const float*>(Wg) + \
                       (size_t)(b * INC + c) * (DC * IND); \
    H8 tL, tH; \
    HD1F(tL,0,0) HD1F(tL,1,1) HD1F(tL,2,2) HD1F(tL,3,3) \
    HD1F(tL,4,4) HD1F(tL,5,5) HD1F(tL,6,6) HD1F(tL,7,7) \
    HD1F(tH,0,8) HD1F(tH,1,9) HD1F(tH,2,10) HD1F(tH,3,11) \
    HD1F(tH,4,12) HD1F(tH,5,13) HD1F(tH,6,14) HD1F(tH,7,15) \
    *reinterpret_cast<h8*>(sm + HATL_OFF + (size_t)(b * INC + c) * 8) = tL.v; \
    *reinterpret_cast<h8*>(sm + HATH_OFF + (size_t)(b * INC + c) * 8) = tH.v; }

    if constexpr (sizeof(WT) == 2) {
        uint4 wA0, wA1, wA2, wA3, wA4, wA5, wA6, wA7;
        uint4 wB0, wB1, wB2, wB3, wB4, wB5, wB6, wB7;
        PREA(0) PREB(0)
        HPIPE(0, 1) HPIPE(1, 2) HPIPE(2, 3) HPIPE(3, 4) HPIPE(4, 5)
        HPIPE(5, 6) HPIPE(6, 7) HPIPE(7, 8) HPIPE(8, 8)
    } else {
        R9(HSTEPF)
    }
    __syncthreads();

    const bool c8 = (cg & 8) != 0, c4 = (cg & 4) != 0;
    const bool c2 = (cg & 2) != 0, c1 = (cg & 1) != 0;

    h8 oLv, oHv;
    HALVE16
    {
        SQUASH1(1.0f / 32.0f, oval)
        OBCAST(oval)
    }

    R9(DECLG)

#define BSTEP(K) { \
    const int c = cg + 16 * (K); \
    H8 hl, hh; \
    hl.v = *reinterpret_cast<const h8*>(sm + HATL_OFF + (size_t)(b * INC + c) * 8); \
    hh.v = *reinterpret_cast<const h8*>(sm + HATH_OFF + (size_t)(b * INC + c) * 8); \
    H8 ol, oh; ol.v = oLv; oh.v = oHv; \
    float dt  = fdot2(hl.p[0], ol.p[0], 0.f); \
    float dt2 = fdot2(hl.p[1], ol.p[1], 0.f); \
    dt  = fdot2(hl.p[2], ol.p[2], dt); \
    dt2 = fdot2(hl.p[3], ol.p[3], dt2); \
    dt  = fdot2(hh.p[0], oh.p[0], dt); \
    dt2 = fdot2(hh.p[1], oh.p[1], dt2); \
    dt  = fdot2(hh.p[2], oh.p[2], dt); \
    dt2 = fdot2(hh.p[3], oh.p[3], dt2); \
    lgr##K += dt + dt2; \
    lg[b * LG_S + c] = (_Float16)lgr##K; }

#define SSTEP(K) { \
    const int c = cg + 16 * (K); \
    float cf = (float)lg[b * LG_S + c]; \
    H8 hl, hh; \
    hl.v = *reinterpret_cast<const h8*>(sm + HATL_OFF + (size_t)(b * INC + c) * 8); \
    hh.v = *reinterpret_cast<const h8*>(sm + HATH_OFF + (size_t)(b * INC + c) * 8); \
    s0  = fmaf(cf, (float)hl.e[0], s0);  s1  = fmaf(cf, (float)hl.e[1], s1); \
    s2  = fmaf(cf, (float)hl.e[2], s2);  s3  = fmaf(cf, (float)hl.e[3], s3); \
    s4  = fmaf(cf, (float)hl.e[4], s4);  s5  = fmaf(cf, (float)hl.e[5], s5); \
    s6  = fmaf(cf, (float)hl.e[6], s6);  s7  = fmaf(cf, (float)hl.e[7], s7); \
    s8  = fmaf(cf, (float)hh.e[0], s8);  s9  = fmaf(cf, (float)hh.e[1], s9); \
    s10 = fmaf(cf, (float)hh.e[2], s10); s11 = fmaf(cf, (float)hh.e[3], s11); \
    s12 = fmaf(cf, (float)hh.e[4], s12); s13 = fmaf(cf, (float)hh.e[5], s13); \
    s14 = fmaf(cf, (float)hh.e[6], s14); s15 = fmaf(cf, (float)hh.e[7], s15); }

    for (int it = 0; it < 2; ++it) {
        R9(BSTEP)
        __syncthreads();

        if (t < 2 * INC) {
            const int c = t >> 1;
            const int rb = (t & 1) * 16;
            R16(SMR)
            float m = fmaxf(v0, v1);
            SMM(2) SMM(3) SMM(4) SMM(5) SMM(6) SMM(7) SMM(8) SMM(9)
            SMM(10) SMM(11) SMM(12) SMM(13) SMM(14) SMM(15)
            m = fmaxf(m, __shfl_xor(m, 1));
            float S = 0.f;
            R16(SME)
            S += __shfl_xor(S, 1);
            float inv = 1.0f / S;
            R16(SMW)
        }
        __syncthreads();

        R16(ZEROS)
        R9(SSTEP)
        HALVE16

        if (it == 0) {
            SQUASH1(1.0f, oval)
            OBCAST(oval)
            __syncthreads();
        } else {
            SQUASH1(1.0f, oval)
            out[(size_t)a * (NC * DC) + t] = oval;
        }
    }
}

extern "C" void kernel_launch(void* const* d_in, const int* in_sizes, int n_in,
                              void* d_out, int out_size, void* d_ws, size_t ws_size,
                              hipStream_t stream) {
    const float* x = (const float*)d_in[0];
    const float* W = (const float*)d_in[1];
    float* out = (float*)d_out;

    if (ws_size >= NEED_BYTES) {
        _Float16* Wh = (_Float16*)d_ws;
        _Float16* hatLg = (_Float16*)((char*)d_ws + WH_BYTES);
        _Float16* hatHg = (_Float16*)((char*)d_ws + WH_BYTES + PLANE_BYTES);
        hipLaunchKernelGGL(convw_kernel, dim3(288), dim3(256), 0, stream, W, Wh);
        hipFuncSetAttribute(reinterpret_cast<const void*>(&hat_kernel),
                            hipFuncAttributeMaxDynamicSharedMemorySize, HSM_BYTES);
        hipLaunchKernelGGL(hat_kernel, dim3(1024), dim3(256), HSM_BYTES, stream,
                           x, Wh, hatLg, hatHg);
        hipFuncSetAttribute(reinterpret_cast<const void*>(&route_kernel),
                            hipFuncAttributeMaxDynamicSharedMemorySize, SMEM_BYTES);
        hipLaunchKernelGGL(route_kernel, dim3(512), dim3(NT), SMEM_BYTES, stream,
                           hatLg, hatHg, out);
    } else if (ws_size >= WH_BYTES) {
        _Float16* Wh = (_Float16*)d_ws;
        hipLaunchKernelGGL(convw_kernel, dim3(288), dim3(256), 0, stream, W, Wh);
        hipFuncSetAttribute(reinterpret_cast<const void*>(&caps_kernel<_Float16>),
                            hipFuncAttributeMaxDynamicSharedMemorySize, SMEM_BYTES);
        hipLaunchKernelGGL(caps_kernel<_Float16>, dim3(512), dim3(NT), SMEM_BYTES,
                           stream, x, Wh, out);
    } else {
        hipFuncSetAttribute(reinterpret_cast<const void*>(&caps_kernel<float>),
                            hipFuncAttributeMaxDynamicSharedMemorySize, SMEM_BYTES);
        hipLaunchKernelGGL(caps_kernel<float>, dim3(512), dim3(NT), SMEM_BYTES,
                           stream, x, W, out);
    }
}

// Round 29
// 44.767 us; speedup vs baseline: 1.9417x; 1.2114x over previous
//
#include <hip/hip_runtime.h>

#define NC 32     // num_capsule
#define DC 16     // dim_capsule
#define INC 144   // input capsules
#define IND 8     // input dim
#define NT 512    // threads: (b 0..31) x (cg 0..15)
#define LG_S 152  // halves per b row of logits

// LDS (halves): hatL[32][144][8] | pad | hatH[32][144][8] | lg[32][152] (x overlaps lg) | o_buf[32][16]
#define HATL_OFF 0
#define HATH_OFF (NC * INC * IND + 8)          // 36872; 16B-aligned
#define LG_OFF (HATH_OFF + NC * INC * IND)     // 73736; 16B-aligned
#define OB_OFF (LG_OFF + NC * LG_S)            // 78600; 16B-aligned
#define SMEM_HALVES (OB_OFF + NC * DC)         // 79112
#define SMEM_BYTES (SMEM_HALVES * 2)           // 158224 <= 163840

typedef _Float16 h2 __attribute__((ext_vector_type(2)));
typedef _Float16 h4v __attribute__((ext_vector_type(4)));
typedef _Float16 h8 __attribute__((ext_vector_type(8)));
typedef float f4 __attribute__((ext_vector_type(4)));

union H8 { h8 v; h2 p[4]; _Float16 e[8]; };
union WU { uint4 u; h8 v; h2 p[4]; };

#if __has_builtin(__builtin_amdgcn_fdot2)
__device__ __forceinline__ float fdot2(h2 a, h2 b, float c) {
    return __builtin_amdgcn_fdot2(a, b, c, false);
}
#else
__device__ __forceinline__ float fdot2(h2 a, h2 b, float c) {
    return c + (float)a[0] * (float)b[0] + (float)a[1] * (float)b[1];
}
#endif

// Convert+TRANSPOSE W: fp32 [b][c][d][i] -> fp16 h8-slots [(b*9+k)*16+d][cg],
// c = cg + 16k. 73728 h8 slots -> grid 288 x 256.
__global__ void convw_kernel(const float* __restrict__ W, _Float16* __restrict__ Wh) {
    int i = blockIdx.x * 256 + threadIdx.x;          // h8 slot 0..73727
    int cg = i & 15, d = (i >> 4) & 15, bk = i >> 8; // bk = b*9+k, 0..287
    int k = bk % 9, b = bk / 9;
    const float* s = W + (((size_t)b * INC + cg + 16 * k) * DC + d) * IND;
    f4 v0 = *reinterpret_cast<const f4*>(s);
    f4 v1 = *reinterpret_cast<const f4*>(s + 4);
    H8 o;
    o.e[0] = (_Float16)v0[0]; o.e[1] = (_Float16)v0[1];
    o.e[2] = (_Float16)v0[2]; o.e[3] = (_Float16)v0[3];
    o.e[4] = (_Float16)v1[0]; o.e[5] = (_Float16)v1[1];
    o.e[6] = (_Float16)v1[2]; o.e[7] = (_Float16)v1[3];
    *reinterpret_cast<h8*>(Wh + (size_t)i * 8) = o.v;
}

#define R9(M)  M(0) M(1) M(2) M(3) M(4) M(5) M(6) M(7) M(8)
#define R16(M) M(0) M(1) M(2) M(3) M(4) M(5) M(6) M(7) M(8) M(9) M(10) M(11) M(12) M(13) M(14) M(15)

template <typename WT>
__global__ __launch_bounds__(NT)
__attribute__((amdgpu_waves_per_eu(2, 4)))
void caps_kernel(const float* __restrict__ xg, const WT* __restrict__ Wg,
                 float* __restrict__ out) {
    extern __shared__ __align__(16) _Float16 sm[];
    _Float16* lg = sm + LG_OFF;
    _Float16* o_buf = sm + OB_OFF;
    _Float16* x_h = lg;  // overlap: x only live during phase H (barrier before lg use)

    const int t = threadIdx.x;
    const int b = t >> 4;    // capsule
    const int cg = t & 15;   // c-group: owns c = cg + 16k, all 16 d
    const int a = blockIdx.x;

    // ---- load x[a]: 1152 floats = 288 f4 -> fp16 LDS ----
    if (t < 288) {
        f4 v = reinterpret_cast<const f4*>(xg + (size_t)a * (INC * IND))[t];
        h4v hv;
        hv[0] = (_Float16)v[0]; hv[1] = (_Float16)v[1];
        hv[2] = (_Float16)v[2]; hv[3] = (_Float16)v[3];
        *reinterpret_cast<h4v*>(x_h + t * 4) = hv;
    }
    __syncthreads();

#define DECLS(D) float s##D;
    R16(DECLS)
#define ZEROS(D) s##D = 0.f;
    R16(ZEROS)

    // ---- Phase H, software-pipelined (r24): 8-deep uint4 double-buffer ----
#define WADDR(K, DG) reinterpret_cast<const uint4*>( \
    reinterpret_cast<const char*>(Wg) + (size_t)(b * 9 + (K)) * 4096 + (DG) * 256 + cg * 16)

#define PREA(K) { wA0 = *WADDR(K,0); wA1 = *WADDR(K,1); wA2 = *WADDR(K,2); \
                  wA3 = *WADDR(K,3); wA4 = *WADDR(K,4); wA5 = *WADDR(K,5); \
                  wA6 = *WADDR(K,6); wA7 = *WADDR(K,7); }
#define PREB(K) { wB0 = *WADDR(K,8); wB1 = *WADDR(K,9); wB2 = *WADDR(K,10); \
                  wB3 = *WADDR(K,11); wB4 = *WADDR(K,12); wB5 = *WADDR(K,13); \
                  wB6 = *WADDR(K,14); wB7 = *WADDR(K,15); }

#define HD1R(WREG, T, E, SD) { \
    WU w; w.u = WREG; \
    float ac = fdot2(w.p[0], xv.p[0], 0.f); \
    ac = fdot2(w.p[1], xv.p[1], ac); \
    ac = fdot2(w.p[2], xv.p[2], ac); \
    ac = fdot2(w.p[3], xv.p[3], ac); \
    T.e[E] = (_Float16)ac; s##SD += ac; }

#define CMPA(T) HD1R(wA0,T,0,0) HD1R(wA1,T,1,1) HD1R(wA2,T,2,2) HD1R(wA3,T,3,3) \
                HD1R(wA4,T,4,4) HD1R(wA5,T,5,5) HD1R(wA6,T,6,6) HD1R(wA7,T,7,7)
#define CMPB(T) HD1R(wB0,T,0,8) HD1R(wB1,T,1,9) HD1R(wB2,T,2,10) HD1R(wB3,T,3,11) \
                HD1R(wB4,T,4,12) HD1R(wB5,T,5,13) HD1R(wB6,T,6,14) HD1R(wB7,T,7,15)

#define HPIPE(K, KN) { \
    const int c = cg + 16 * (K); \
    H8 xv; xv.v = *reinterpret_cast<const h8*>(x_h + c * IND); \
    H8 tL, tH; \
    CMPA(tL) \
    PREA(KN) \
    CMPB(tH) \
    PREB(KN) \
    *reinterpret_cast<h8*>(sm + HATL_OFF + (size_t)(b * INC + c) * 8) = tL.v; \
    *reinterpret_cast<h8*>(sm + HATH_OFF + (size_t)(b * INC + c) * 8) = tH.v; }

#define HD1F(T, E, DG) { \
    const float* wf = wfr + (DG) * IND; \
    f4 w0 = *reinterpret_cast<const f4*>(wf); \
    f4 w1 = *reinterpret_cast<const f4*>(wf + 4); \
    float ac = (float)xv.e[0] * w0[0]; \
    ac = fmaf((float)xv.e[1], w0[1], ac); \
    ac = fmaf((float)xv.e[2], w0[2], ac); \
    ac = fmaf((float)xv.e[3], w0[3], ac); \
    ac = fmaf((float)xv.e[4], w1[0], ac); \
    ac = fmaf((float)xv.e[5], w1[1], ac); \
    ac = fmaf((float)xv.e[6], w1[2], ac); \
    ac = fmaf((float)xv.e[7], w1[3], ac); \
    T.e[E] = (_Float16)ac; s##DG += ac; }

#define HSTEPF(K) { \
    const int c = cg + 16 * (K); \
    H8 xv; xv.v = *reinterpret_cast<const h8*>(x_h + c * IND); \
    const float* wfr = reinterpret_cast<const float*>(Wg) + \
                       (size_t)(b * INC + c) * (DC * IND); \
    H8 tL, tH; \
    HD1F(tL,0,0) HD1F(tL,1,1) HD1F(tL,2,2) HD1F(tL,3,3) \
    HD1F(tL,4,4) HD1F(tL,5,5) HD1F(tL,6,6) HD1F(tL,7,7) \
    HD1F(tH,0,8) HD1F(tH,1,9) HD1F(tH,2,10) HD1F(tH,3,11) \
    HD1F(tH,4,12) HD1F(tH,5,13) HD1F(tH,6,14) HD1F(tH,7,15) \
    *reinterpret_cast<h8*>(sm + HATL_OFF + (size_t)(b * INC + c) * 8) = tL.v; \
    *reinterpret_cast<h8*>(sm + HATH_OFF + (size_t)(b * INC + c) * 8) = tH.v; }

    if constexpr (sizeof(WT) == 2) {
        uint4 wA0, wA1, wA2, wA3, wA4, wA5, wA6, wA7;
        uint4 wB0, wB1, wB2, wB3, wB4, wB5, wB6, wB7;
        PREA(0) PREB(0)
        HPIPE(0, 1) HPIPE(1, 2) HPIPE(2, 3) HPIPE(3, 4) HPIPE(4, 5)
        HPIPE(5, 6) HPIPE(6, 7) HPIPE(7, 8) HPIPE(8, 8)  // last: benign reload
    } else {
        R9(HSTEPF)
    }
    __syncthreads();  // x_h reads done everywhere before B-pass writes lg (overlap)

    const bool c8 = (cg & 8) != 0, c4 = (cg & 4) != 0;
    const bool c2 = (cg & 2) != 0, c1 = (cg & 1) != 0;
#define HV(A, B, M, CB) { float snd_ = (CB) ? s##A : s##B; \
                          float kp_ = (CB) ? s##B : s##A; \
                          s##A = kp_ + __shfl_xor(snd_, M, 16); }
#define HALVE16 \
    HV(0,8,8,c8) HV(1,9,8,c8) HV(2,10,8,c8) HV(3,11,8,c8) \
    HV(4,12,8,c8) HV(5,13,8,c8) HV(6,14,8,c8) HV(7,15,8,c8) \
    HV(0,4,4,c4) HV(1,5,4,c4) HV(2,6,4,c4) HV(3,7,4,c4) \
    HV(0,2,2,c2) HV(1,3,2,c2) \
    HV(0,1,1,c1)

#define SQUASH1(RS, OVAL) \
    float r_ = s0 * (RS); \
    float n2_ = r_ * r_; \
    n2_ += __shfl_xor(n2_, 1, 16); n2_ += __shfl_xor(n2_, 2, 16); \
    n2_ += __shfl_xor(n2_, 4, 16); n2_ += __shfl_xor(n2_, 8, 16); \
    float OVAL = r_ * (n2_ / ((1.0f + n2_) * sqrtf(n2_ + 1e-7f)));

#define OBCAST(OVAL) \
    o_buf[b * DC + cg] = (_Float16)(OVAL); \
    __threadfence_block(); \
    oLv = *reinterpret_cast<const h8*>(o_buf + b * DC); \
    oHv = *reinterpret_cast<const h8*>(o_buf + b * DC + 8);

    h8 oLv, oHv;
    HALVE16
    {
        SQUASH1(1.0f / 32.0f, oval)  // softmax(0) uniform coefficients
        OBCAST(oval)
    }

#define DECLG(K) float lgr##K = 0.f;
    R9(DECLG)

    // ---- B-pass, LOAD-BATCHED: issue all 18 ds_read_b128 back-to-back into
    // NAMED regs (latencies overlap; r25's VGPR=60 allocation serialized
    // them), then compute. Demand ~90 regs < 128 granted budget. ----
#define BL(K) uint4 bl##K = *reinterpret_cast<const uint4*>( \
                  sm + HATL_OFF + (size_t)(b * INC + cg + 16 * (K)) * 8), \
              bh##K = *reinterpret_cast<const uint4*>( \
                  sm + HATH_OFF + (size_t)(b * INC + cg + 16 * (K)) * 8);

#define BC(K) { \
    WU hl, hh; hl.u = bl##K; hh.u = bh##K; \
    H8 ol, oh; ol.v = oLv; oh.v = oHv; \
    float dt  = fdot2(hl.p[0], ol.p[0], 0.f); \
    float dt2 = fdot2(hl.p[1], ol.p[1], 0.f); \
    dt  = fdot2(hl.p[2], ol.p[2], dt); \
    dt2 = fdot2(hl.p[3], ol.p[3], dt2); \
    dt  = fdot2(hh.p[0], oh.p[0], dt); \
    dt2 = fdot2(hh.p[1], oh.p[1], dt2); \
    dt  = fdot2(hh.p[2], oh.p[2], dt); \
    dt2 = fdot2(hh.p[3], oh.p[3], dt2); \
    lgr##K += dt + dt2; \
    lg[b * LG_S + cg + 16 * (K)] = (_Float16)lgr##K; }

    // ---- S-pass, LOAD-BATCHED similarly (9 cf + 18 rows up-front) ----
#define SL(K) float cf##K = (float)lg[b * LG_S + cg + 16 * (K)]; \
              uint4 sl##K = *reinterpret_cast<const uint4*>( \
                  sm + HATL_OFF + (size_t)(b * INC + cg + 16 * (K)) * 8), \
              sh##K = *reinterpret_cast<const uint4*>( \
                  sm + HATH_OFF + (size_t)(b * INC + cg + 16 * (K)) * 8);

#define SC(K) { \
    WU hl, hh; hl.u = sl##K; hh.u = sh##K; \
    H8 hle, hhe; hle.v = hl.v; hhe.v = hh.v; \
    s0  = fmaf(cf##K, (float)hle.e[0], s0);  s1  = fmaf(cf##K, (float)hle.e[1], s1); \
    s2  = fmaf(cf##K, (float)hle.e[2], s2);  s3  = fmaf(cf##K, (float)hle.e[3], s3); \
    s4  = fmaf(cf##K, (float)hle.e[4], s4);  s5  = fmaf(cf##K, (float)hle.e[5], s5); \
    s6  = fmaf(cf##K, (float)hle.e[6], s6);  s7  = fmaf(cf##K, (float)hle.e[7], s7); \
    s8  = fmaf(cf##K, (float)hhe.e[0], s8);  s9  = fmaf(cf##K, (float)hhe.e[1], s9); \
    s10 = fmaf(cf##K, (float)hhe.e[2], s10); s11 = fmaf(cf##K, (float)hhe.e[3], s11); \
    s12 = fmaf(cf##K, (float)hhe.e[4], s12); s13 = fmaf(cf##K, (float)hhe.e[5], s13); \
    s14 = fmaf(cf##K, (float)hhe.e[6], s14); s15 = fmaf(cf##K, (float)hhe.e[7], s15); }

    for (int it = 0; it < 2; ++it) {
        {
            R9(BL)   // 18 b128 loads issued together
            R9(BC)   // then compute
        }
        __syncthreads();

        // softmax over 32 capsules: 2 threads per c, 16 bb's each, named regs
        if (t < 2 * INC) {
            const int c = t >> 1;
            const int rb = (t & 1) * 16;
#define SMR(I) float v##I = (float)lg[(rb + I) * LG_S + c];
            R16(SMR)
            float m = fmaxf(v0, v1);
#define SMM(I) m = fmaxf(m, v##I);
            SMM(2) SMM(3) SMM(4) SMM(5) SMM(6) SMM(7) SMM(8) SMM(9)
            SMM(10) SMM(11) SMM(12) SMM(13) SMM(14) SMM(15)
            m = fmaxf(m, __shfl_xor(m, 1));
            float S = 0.f;
#define SME(I) v##I = __expf(v##I - m); S += v##I;
            R16(SME)
            S += __shfl_xor(S, 1);
            float inv = 1.0f / S;
#define SMW(I) lg[(rb + I) * LG_S + c] = (_Float16)(v##I * inv);
            R16(SMW)
        }
        __syncthreads();

        R16(ZEROS)
        {
            R9(SL)   // 9 u16 + 18 b128 loads issued together
            R9(SC)
        }
        HALVE16

        if (it == 0) {
            SQUASH1(1.0f, oval)
            OBCAST(oval)
            __syncthreads();  // S-reads of lg done before next B-pass writes
        } else {
            SQUASH1(1.0f, oval)
            out[(size_t)a * (NC * DC) + t] = oval;  // lane cg = dim cg: coalesced
        }
    }
}

extern "C" void kernel_launch(void* const* d_in, const int* in_sizes, int n_in,
                              void* d_out, int out_size, void* d_ws, size_t ws_size,
                              hipStream_t stream) {
    const float* x = (const float*)d_in[0];
    const float* W = (const float*)d_in[1];
    float* out = (float*)d_out;

    const size_t WH_BYTES = (size_t)NC * INC * DC * IND * 2;  // 1179648

    if (ws_size >= WH_BYTES) {
        _Float16* Wh = (_Float16*)d_ws;
        hipLaunchKernelGGL(convw_kernel, dim3(288), dim3(256), 0, stream, W, Wh);
        hipFuncSetAttribute(reinterpret_cast<const void*>(&caps_kernel<_Float16>),
                            hipFuncAttributeMaxDynamicSharedMemorySize, SMEM_BYTES);
        hipLaunchKernelGGL(caps_kernel<_Float16>, dim3(512), dim3(NT), SMEM_BYTES,
                           stream, x, Wh, out);
    } else {
        hipFuncSetAttribute(reinterpret_cast<const void*>(&caps_kernel<float>),
                            hipFuncAttributeMaxDynamicSharedMemorySize, SMEM_BYTES);
        hipLaunchKernelGGL(caps_kernel<float>, dim3(512), dim3(NT), SMEM_BYTES,
                           stream, x, W, out);
    }
}